// Round 13
// baseline (48.150 us; speedup 1.0000x reference)
//
#include <hip/hip_runtime.h>
#include <math.h>
#include <stdint.h>

#define NIMG 8
#define HH 1024
#define WW 1024
#define NPIX (HH*WW)
#define PAIRS 10000
#define STRIP 8
#define NSTRIPS 128          // strips per image (rows 1..1022, 8 rows each)
#define S1BLOCKS 40          // sample blocks per image

// ws layout (floats). EVERY atomic word on its OWN 128B line (32-float
// stride) — R11's regression was ~660 RMWs from 8 XCDs serializing on ONE
// shared line; padded per-image lines are touched by one XCD only.
// [OFF_EDGE .. +1024)      per-strip squared-sobel max (plain stores, k1)
// [OFF_MDI  + img*32]      per-image maxdiff bits (uint atomicMax)
// [OFF_DONE + img*32]      per-image done counters (uint)
// [OFF_GL]                 global Sum(L_i) (float atomic), own line
// [OFF_GC]                 global Sum(cnt) (float atomic), own line
// [OFF_IMGD]               image-finisher counter (uint), own line
// byte 65536:                recsA [NIMG*PAIRS] float4 (d2_0,d2_1,d2_2,un)
// byte 65536+NIMG*PAIRS*16:  recsB [NIMG*PAIRS] float4 (ad_0,ad_1,ad_2,cnt)
//
// XCD note: both kernels use img = blockIdx.x & 7 — an image's blocks,
// records, finisher, and its MDI/DONE lines stay on ONE XCD (R10: ~6 µs win).
// Records are dense fixed-slot, rewritten identically each replay.
#define OFF_EDGE 0
#define OFF_MDI  4096        // img*32
#define OFF_DONE 4352        // img*32
#define OFF_GL   4608
#define OFF_GC   4640
#define OFF_IMGD 4672
#define ZERO_N   608         // zero ws[4096 .. 4704)

__device__ __forceinline__ uint64_t mix64(uint64_t x){
    x += 0x9E3779B97F4A7C15ull;
    x = (x ^ (x >> 30)) * 0xBF58476D1CE4E5B9ull;
    x = (x ^ (x >> 27)) * 0x94D049BB133111EBull;
    return x ^ (x >> 31);
}

__device__ __forceinline__ float block_reduce_max(float v, float* sm){
    for (int off = 32; off; off >>= 1)
        v = fmaxf(v, __shfl_down(v, off));
    int wv = threadIdx.x >> 6, lane = threadIdx.x & 63;
    if (lane == 0) sm[wv] = v;
    __syncthreads();
    if (threadIdx.x == 0)
        sm[0] = fmaxf(fmaxf(sm[0], sm[1]), fmaxf(sm[2], sm[3]));
    __syncthreads();
    float r = sm[0];
    __syncthreads();
    return r;
}

__device__ __forceinline__ float block_reduce_sum(float v, float* sm){
    for (int off = 32; off; off >>= 1)
        v += __shfl_down(v, off);
    int wv = threadIdx.x >> 6, lane = threadIdx.x & 63;
    if (lane == 0) sm[wv] = v;
    __syncthreads();
    if (threadIdx.x == 0)
        sm[0] = sm[0] + sm[1] + sm[2] + sm[3];
    __syncthreads();
    float r = sm[0];
    __syncthreads();
    return r;
}

__device__ __forceinline__ void load16(const float* __restrict__ p, float* d){
    const float4* q = (const float4*)p;
    float4 v0 = q[0], v1 = q[1], v2 = q[2], v3 = q[3];
    d[0]=v0.x; d[1]=v0.y; d[2]=v0.z; d[3]=v0.w;
    d[4]=v1.x; d[5]=v1.y; d[6]=v1.z; d[7]=v1.w;
    d[8]=v2.x; d[9]=v2.y; d[10]=v2.z; d[11]=v2.w;
    d[12]=v3.x; d[13]=v3.y; d[14]=v3.z; d[15]=v3.w;
}

// One wave owns a 1024-wide row span (16 cols/lane), rolls 3 rows in registers,
// separable sobel, cross-lane neighbors via shuffles, max of SQUARED magnitude.
// Block 0 zeroes this launch's (padded) atomic slots.
__global__ __launch_bounds__(256) void edgemax_kernel(const float* __restrict__ images,
                                                      float* __restrict__ ws){
    if (blockIdx.x == 0){
        for (int i = threadIdx.x; i < ZERO_N; i += 256)
            ws[OFF_MDI + i] = 0.0f;
    }

    int img  = blockIdx.x & 7;                          // XCD-pinned
    int xb   = blockIdx.x >> 3;                         // 0..31
    const float* x = images + (size_t)img * 3 * NPIX;   // channel 0
    int wv   = threadIdx.x >> 6;
    int lane = threadIdx.x & 63;
    int strip = xb * 4 + wv;                            // 0..127
    int r0 = 1 + strip * STRIP;
    int r1 = min(r0 + STRIP - 1, HH - 2);
    int c0 = lane * 16;

    float a[16], b[16], n[16];
    load16(x + (size_t)(r0-1)*WW + c0, a);
    load16(x + (size_t)r0*WW + c0, b);

    float m = 0.0f;
    for (int r = r0; r <= r1; ++r){
        load16(x + (size_t)(r+1)*WW + c0, n);
        float sx[16], dy[16];
        #pragma unroll
        for (int i = 0; i < 16; ++i){
            sx[i] = a[i] + 2.0f*b[i] + n[i];
            dy[i] = a[i] - n[i];
        }
        float sxl = __shfl_up(sx[15], 1);
        float sxr = __shfl_down(sx[0], 1);
        float dyl = __shfl_up(dy[15], 1);
        float dyr = __shfl_down(dy[0], 1);
        #pragma unroll
        for (int j = 0; j < 16; ++j){
            float sl = (j == 0)  ? sxl : sx[j-1];
            float sr = (j == 15) ? sxr : sx[j+1];
            float dl = (j == 0)  ? dyl : dy[j-1];
            float dr = (j == 15) ? dyr : dy[j+1];
            float gx = sr - sl;
            float gy = dl + 2.0f*dy[j] + dr;
            float e2 = gx*gx + gy*gy;
            int c = c0 + j;
            if (c >= 1 && c <= WW-2) m = fmaxf(m, e2);
        }
        #pragma unroll
        for (int i = 0; i < 16; ++i){ a[i] = b[i]; b[i] = n[i]; }
    }
    for (int off = 32; off; off >>= 1)
        m = fmaxf(m, __shfl_down(m, off));
    if (lane == 0)
        ws[OFF_EDGE + img * NSTRIPS + strip] = m;
}

// One rejection attempt's loaded state (all loads issued eagerly, clamped).
struct AttLd {
    int r, c, rl, cl;
    float a, b, cc, d, e, f, g, h, dg, tg;
};

__device__ __forceinline__ AttLd att_issue(uint64_t u,
        const float* __restrict__ x, const float* __restrict__ tgt,
        const float* __restrict__ dgt){
    AttLd s;
    uint32_t pix = (uint32_t)(u >> 44);                // 20-bit uniform
    s.r  = (int)(pix >> 10);
    s.c  = (int)(pix & (WW - 1));
    s.rl = min(max(s.r, 1), HH-2);
    s.cl = min(max(s.c, 1), WW-2);
    const float* p0 = x + (size_t)(s.rl-1)*WW + s.cl;
    const float* p1 = x + (size_t)s.rl*WW + s.cl;
    const float* p2 = x + (size_t)(s.rl+1)*WW + s.cl;
    s.a = p0[-1]; s.b = p0[0]; s.cc = p0[1];
    s.d = p1[-1];               s.e = p1[1];
    s.f = p2[-1]; s.g = p2[0];  s.h = p2[1];
    s.dg = dgt[s.rl*WW + s.cl];
    s.tg = tgt[s.rl*WW + s.cl];
    return s;
}

// Sample (1 thread/pair, pipelined serial rejection) + dense records; the
// 40th-arriver block per image finishes that image from XCD-local records;
// the 8th image finisher writes out. All rendezvous words padded to private
// 128B lines; ordering via __syncthreads' vmcnt drain + explicit s_waitcnt.
__global__ __launch_bounds__(256) void sample_finish_kernel(
                               const float* __restrict__ inputs,
                               const float* __restrict__ targets,
                               const float* __restrict__ images,
                               const float* __restrict__ depth_gt,
                               float* __restrict__ ws,
                               float4* __restrict__ recsA,
                               float4* __restrict__ recsB,
                               float* __restrict__ out){
    __shared__ float sred[4];
    __shared__ unsigned flag1;
    int img = blockIdx.x & 7;                 // XCD-pinned (same XCD as edgemax)
    int jb  = blockIdx.x >> 3;                // 0..39
    int tid = threadIdx.x;
    int j   = jb * 256 + tid;
    const float* x   = images   + (size_t)img * 3 * NPIX;
    const float* inp = inputs   + (size_t)img * NPIX;
    const float* tgt = targets  + (size_t)img * NPIX;
    const float* dgt = depth_gt + (size_t)img * NPIX;

    float ev = 0.0f;
    if (tid < NSTRIPS) ev = ws[OFF_EDGE + img * NSTRIPS + tid];
    float thr2 = 0.01f * block_reduce_max(ev, sred);

    float mdiff = 0.0f;
    float4 recA = make_float4(0.f, 0.f, 0.f, 0.f);   // d2[3], un
    float4 recB = make_float4(0.f, 0.f, 0.f, 0.f);   // ad[3], cnt

    if (j < PAIRS){
        uint64_t base = ((uint64_t)(img * PAIRS + j)) << 10;
        bool pdir = (mix64(((uint64_t)(NIMG * PAIRS + img)) << 10) & 1ull) != 0ull;

        int sh = -1, sw = -1;
        float gxs = 0.f, gys = 0.f, e2s = 1.f;

        AttLd cur = att_issue(mix64(base + 0ull), x, tgt, dgt);
        for (int att = 0; att < 900; ++att){
            AttLd nxt = att_issue(mix64(base + (uint64_t)(att + 1)), x, tgt, dgt);
            float gx = (cur.cc - cur.a) + 2.0f*(cur.e - cur.d) + (cur.h - cur.f);
            float gy = (cur.a + 2.0f*cur.b + cur.cc) - (cur.f + 2.0f*cur.g + cur.h);
            float e2 = gx*gx + gy*gy;
            bool pass = (cur.r == cur.rl) && (cur.c == cur.cl) && (e2 >= thr2) &&
                        (cur.dg > -0.001f && cur.dg < 80.0f) && (cur.tg != 80.0f);
            if (pass){
                sh = cur.rl; sw = cur.cl; gxs = gx; gys = gy; e2s = e2;
                break;
            }
            cur = nxt;
        }

        if (sh >= 0){
            float inv = rsqrtf(e2s);
            float cmul = gxs * inv;
            float rmul = gys * inv;
            if (!pdir) cmul = -cmul;

            uint64_t u0 = mix64(base + 1000ull);
            uint64_t u1 = mix64(base + 1001ull);
            float dist[4];
            dist[0] = -(float)(2u + (uint32_t)(u0 & 0xFFFFFFFFull) % 29u);
            dist[1] = -(float)(2u + (uint32_t)(u0 >> 32) % 29u);
            dist[2] =  (float)(2u + (uint32_t)(u1 & 0xFFFFFFFFull) % 29u);
            dist[3] =  (float)(2u + (uint32_t)(u1 >> 32) % 29u);

            int rowc[4], colc[4];
            bool valid = true;
            #pragma unroll
            for (int k = 0; k < 4; ++k){
                int cc2 = sw + (int)rintf(dist[k] * cmul);
                int rr2 = sh + (int)rintf(dist[k] * rmul);
                if (cc2 < 0 || cc2 > WW-1 || rr2 < 0 || rr2 > HH-1) valid = false;
                colc[k] = min(max(cc2, 0), WW-1);
                rowc[k] = min(max(rr2, 0), HH-1);
            }

            if (valid){
                float t4[4], i4[4];
                #pragma unroll
                for (int k = 0; k < 4; ++k){
                    int p = rowc[k]*WW + colc[k];
                    t4[k] = tgt[p];
                    i4[k] = inp[p];
                }
                float d2a[3], ada[3];
                float un = 0.0f;
                #pragma unroll
                for (int k = 0; k < 3; ++k){
                    float tA = t4[k], tB = t4[k+1];
                    float ratio = (tA + 1e-6f) / (tB + 1e-6f);
                    float adk = fabsf(tA - tB);
                    mdiff = fmaxf(mdiff, adk);
                    bool eq = (ratio < 1.03f) && (ratio > 0.9708737864077669f);
                    if (eq){
                        float d = i4[k] - i4[k+1];
                        d2a[k] = d*d; ada[k] = adk;
                    } else {
                        d2a[k] = 0.f; ada[k] = 0.f;
                        float lab = (ratio >= 1.03f) ? 1.0f : -1.0f;
                        un += log1pf(expf((i4[k+1] - i4[k]) * lab));
                    }
                }
                recA = make_float4(d2a[0], d2a[1], d2a[2], un);
                recB = make_float4(ada[0], ada[1], ada[2], 3.0f);
            }
        }
        recsA[img * PAIRS + j] = recA;
        recsB[img * PAIRS + j] = recB;
    }

    // ---- per-block rendezvous (padded per-image lines, same-XCD only) ----
    float mdb = block_reduce_max(mdiff, sred);  // __syncthreads inside drains
                                                // ALL waves' record stores to L2
    if (tid == 0){
        if (mdb > 0.0f)
            atomicMax((unsigned int*)&ws[OFF_MDI + img*32], __float_as_uint(mdb));
        asm volatile("s_waitcnt vmcnt(0)" ::: "memory");   // max lands before done
        unsigned old = atomicAdd((unsigned int*)&ws[OFF_DONE + img*32], 1u);
        flag1 = (old == (unsigned)(S1BLOCKS - 1)) ? 1u : 0u;
    }
    __syncthreads();

    // ---- 40th arriver: finish this image from L2-local records ----
    if (flag1){
        float md = __uint_as_float(
            atomicAdd((unsigned int*)&ws[OFF_MDI + img*32], 0u));
        float inv = 1.0f / (md + 1e-6f);

        float loss = 0.0f, cnt = 0.0f;
        for (int r = tid; r < PAIRS; r += 256){
            float4 A = recsA[img * PAIRS + r];
            float4 B = recsB[img * PAIRS + r];
            loss += A.w
                  + A.x * expf(-B.x * inv)
                  + A.y * expf(-B.y * inv)
                  + A.z * expf(-B.z * inv);
            cnt  += B.w;
        }
        loss = block_reduce_sum(loss, sred);
        cnt  = block_reduce_sum(cnt, sred);

        if (tid == 0){
            float Li = loss / fmaxf(cnt, 1.0f);   // ALPHA = 1
            atomicAdd(&ws[OFF_GL], Li);
            atomicAdd(&ws[OFF_GC], cnt);
            asm volatile("s_waitcnt vmcnt(0)" ::: "memory");
            unsigned o2 = atomicAdd((unsigned int*)&ws[OFF_IMGD], 1u);
            if (o2 == (unsigned)(NIMG - 1)){
                float gl = atomicAdd(&ws[OFF_GL], 0.0f);
                float gc = atomicAdd(&ws[OFF_GC], 0.0f);
                out[0] = gl / (float)NIMG;
                out[1] = gc / (float)NIMG;
            }
        }
    }
}

extern "C" void kernel_launch(void* const* d_in, const int* in_sizes, int n_in,
                              void* d_out, int out_size, void* d_ws, size_t ws_size,
                              hipStream_t stream) {
    const float* inputs  = (const float*)d_in[0];
    const float* targets = (const float*)d_in[1];
    const float* images  = (const float*)d_in[2];
    const float* depth   = (const float*)d_in[3];
    float* out = (float*)d_out;

    float* ws     = (float*)d_ws;
    float4* recsA = (float4*)((char*)d_ws + 65536);
    float4* recsB = recsA + (size_t)NIMG * PAIRS;

    hipLaunchKernelGGL(edgemax_kernel, dim3(NSTRIPS/4 * NIMG), dim3(256), 0, stream,
                       images, ws);
    hipLaunchKernelGGL(sample_finish_kernel, dim3(S1BLOCKS * NIMG), dim3(256), 0, stream,
                       inputs, targets, images, depth, ws, recsA, recsB, out);
}

// Round 14
// 46.032 us; speedup vs baseline: 1.0460x; 1.0460x over previous
//
#include <hip/hip_runtime.h>
#include <math.h>
#include <stdint.h>

#define NIMG 8
#define HH 1024
#define WW 1024
#define NPIX (HH*WW)
#define PAIRS 10000
#define STRIP 8
#define NSTRIPS 128          // strips per image (rows 1..1022, 8 rows each)
#define SBLK 160             // sample blocks per image (160*256/4 = 10240 pairs)
#define PSTRIDE 640          // per-wave partial slots per image (160*4)
#define FBLK 4               // finish blocks per image
#define QREC (PAIRS*4/FBLK)  // record entries per finish block (10000)
#define QSLOT (PSTRIDE/FBLK) // partial slots per finish block (160)

// ws layout (floats):
// [OFF_EDGE .. +1024)    per-strip squared-sobel max (plain stores, k1)
// [OFF_MD  + img*640)    per-wave maxdiff partials (plain stores, k2)
// [OFF_UN  + img*640)    per-wave unequal-loss partials
// [OFF_CNT + img*640)    per-wave count partials
// [OFF_RES + img*32]     per-image {loss,cnt} atomic accum — own 128B line
// [OFF_CTR]              finish completion counter, own line
// byte 131072: recs float2[NIMG][PAIRS*4] = {d2, ad} per (pair, endpoint-lane)
//
// XCD note: k1/k2/k3 all use img = blockIdx.x & 7 — an image's blocks and
// records stay on ONE XCD's L2 (R10: ~6 µs win).
//
// k2 TLP scheme: 4 lanes per pair run the SAME rejection attempt redundantly
// (identical addresses -> coalesced, ZERO extra line traffic vs 1 thread/pair)
// giving 4x waves (5/SIMD) and E[max over 16] straggler rounds instead of
// E[max over 64]; the endpoint phase then splits genuinely (1 endpoint/lane).
#define OFF_EDGE 0
#define OFF_MD   1024
#define OFF_UN   6144
#define OFF_CNT  11264
#define OFF_RES  16384
#define OFF_CTR  16640

__device__ __forceinline__ uint64_t mix64(uint64_t x){
    x += 0x9E3779B97F4A7C15ull;
    x = (x ^ (x >> 30)) * 0xBF58476D1CE4E5B9ull;
    x = (x ^ (x >> 27)) * 0x94D049BB133111EBull;
    return x ^ (x >> 31);
}

__device__ __forceinline__ float block_reduce_max(float v, float* sm){
    for (int off = 32; off; off >>= 1)
        v = fmaxf(v, __shfl_down(v, off));
    int wv = threadIdx.x >> 6, lane = threadIdx.x & 63;
    if (lane == 0) sm[wv] = v;
    __syncthreads();
    if (threadIdx.x == 0)
        sm[0] = fmaxf(fmaxf(sm[0], sm[1]), fmaxf(sm[2], sm[3]));
    __syncthreads();
    float r = sm[0];
    __syncthreads();
    return r;
}

__device__ __forceinline__ float block_reduce_sum(float v, float* sm){
    for (int off = 32; off; off >>= 1)
        v += __shfl_down(v, off);
    int wv = threadIdx.x >> 6, lane = threadIdx.x & 63;
    if (lane == 0) sm[wv] = v;
    __syncthreads();
    if (threadIdx.x == 0)
        sm[0] = sm[0] + sm[1] + sm[2] + sm[3];
    __syncthreads();
    float r = sm[0];
    __syncthreads();
    return r;
}

__device__ __forceinline__ void load16(const float* __restrict__ p, float* d){
    const float4* q = (const float4*)p;
    float4 v0 = q[0], v1 = q[1], v2 = q[2], v3 = q[3];
    d[0]=v0.x; d[1]=v0.y; d[2]=v0.z; d[3]=v0.w;
    d[4]=v1.x; d[5]=v1.y; d[6]=v1.z; d[7]=v1.w;
    d[8]=v2.x; d[9]=v2.y; d[10]=v2.z; d[11]=v2.w;
    d[12]=v3.x; d[13]=v3.y; d[14]=v3.z; d[15]=v3.w;
}

// One wave owns a 1024-wide row span (16 cols/lane), rolls 3 rows in registers,
// separable sobel, cross-lane neighbors via shuffles, max of SQUARED magnitude.
// Block 0 zeroes this launch's atomic slots.
__global__ __launch_bounds__(256) void edgemax_kernel(const float* __restrict__ images,
                                                      float* __restrict__ ws){
    if (blockIdx.x == 0){
        for (int i = threadIdx.x; i < 288; i += 256)
            ws[OFF_RES + i] = 0.0f;               // padded RES slots + CTR
    }

    int img  = blockIdx.x & 7;                          // XCD-pinned
    int xb   = blockIdx.x >> 3;                         // 0..31
    const float* x = images + (size_t)img * 3 * NPIX;   // channel 0
    int wv   = threadIdx.x >> 6;
    int lane = threadIdx.x & 63;
    int strip = xb * 4 + wv;                            // 0..127
    int r0 = 1 + strip * STRIP;
    int r1 = min(r0 + STRIP - 1, HH - 2);
    int c0 = lane * 16;

    float a[16], b[16], n[16];
    load16(x + (size_t)(r0-1)*WW + c0, a);
    load16(x + (size_t)r0*WW + c0, b);

    float m = 0.0f;
    for (int r = r0; r <= r1; ++r){
        load16(x + (size_t)(r+1)*WW + c0, n);
        float sx[16], dy[16];
        #pragma unroll
        for (int i = 0; i < 16; ++i){
            sx[i] = a[i] + 2.0f*b[i] + n[i];
            dy[i] = a[i] - n[i];
        }
        float sxl = __shfl_up(sx[15], 1);
        float sxr = __shfl_down(sx[0], 1);
        float dyl = __shfl_up(dy[15], 1);
        float dyr = __shfl_down(dy[0], 1);
        #pragma unroll
        for (int j = 0; j < 16; ++j){
            float sl = (j == 0)  ? sxl : sx[j-1];
            float sr = (j == 15) ? sxr : sx[j+1];
            float dl = (j == 0)  ? dyl : dy[j-1];
            float dr = (j == 15) ? dyr : dy[j+1];
            float gx = sr - sl;
            float gy = dl + 2.0f*dy[j] + dr;
            float e2 = gx*gx + gy*gy;
            int c = c0 + j;
            if (c >= 1 && c <= WW-2) m = fmaxf(m, e2);
        }
        #pragma unroll
        for (int i = 0; i < 16; ++i){ a[i] = b[i]; b[i] = n[i]; }
    }
    for (int off = 32; off; off >>= 1)
        m = fmaxf(m, __shfl_down(m, off));
    if (lane == 0)
        ws[OFF_EDGE + img * NSTRIPS + strip] = m;
}

// One rejection attempt's loaded state (loads issued eagerly, clamped).
struct AttLd {
    int r, c, rl, cl;
    float a, b, cc, d, e, f, g, h, dg, tg;
};

__device__ __forceinline__ AttLd att_issue(uint64_t u,
        const float* __restrict__ x, const float* __restrict__ tgt,
        const float* __restrict__ dgt){
    AttLd s;
    uint32_t pix = (uint32_t)(u >> 44);                // 20-bit uniform
    s.r  = (int)(pix >> 10);
    s.c  = (int)(pix & (WW - 1));
    s.rl = min(max(s.r, 1), HH-2);
    s.cl = min(max(s.c, 1), WW-2);
    const float* p0 = x + (size_t)(s.rl-1)*WW + s.cl;
    const float* p1 = x + (size_t)s.rl*WW + s.cl;
    const float* p2 = x + (size_t)(s.rl+1)*WW + s.cl;
    s.a = p0[-1]; s.b = p0[0]; s.cc = p0[1];
    s.d = p1[-1];               s.e = p1[1];
    s.f = p2[-1]; s.g = p2[0];  s.h = p2[1];
    s.dg = dgt[s.rl*WW + s.cl];
    s.tg = tgt[s.rl*WW + s.cl];
    return s;
}

// 4 lanes per pair; all 4 run the SAME serial rejection (group-uniform, same
// addresses -> one coalesced request). After acceptance each lane owns one
// endpoint. Selection order identical to the 1-thread serial loop.
__global__ __launch_bounds__(256) void sample_kernel(
                               const float* __restrict__ inputs,
                               const float* __restrict__ targets,
                               const float* __restrict__ images,
                               const float* __restrict__ depth_gt,
                               float* __restrict__ ws,
                               float2* __restrict__ recs){
    __shared__ float sred[4];
    int img  = blockIdx.x & 7;                // XCD-pinned
    int jb   = blockIdx.x >> 3;               // 0..159
    int tid  = threadIdx.x;
    int lane = tid & 63;
    int grpb = lane & ~3;
    int g    = jb * 256 + tid;                // 0..40959
    int j    = g >> 2;                        // pair index
    int sub  = g & 3;
    const float* x   = images   + (size_t)img * 3 * NPIX;
    const float* inp = inputs   + (size_t)img * NPIX;
    const float* tgt = targets  + (size_t)img * NPIX;
    const float* dgt = depth_gt + (size_t)img * NPIX;

    float ev = 0.0f;
    if (tid < NSTRIPS) ev = ws[OFF_EDGE + img * NSTRIPS + tid];
    float thr2 = 0.01f * block_reduce_max(ev, sred);

    float mdiff = 0.0f, un = 0.0f, cntv = 0.0f;
    float d2 = 0.0f, ad = 0.0f;

    if (j < PAIRS){
        uint64_t base = ((uint64_t)(img * PAIRS + j)) << 10;
        bool pdir = (mix64(((uint64_t)(NIMG * PAIRS + img)) << 10) & 1ull) != 0ull;

        int sh = -1, sw = -1;
        float gxs = 0.f, gys = 0.f, e2s = 1.f;

        AttLd cur = att_issue(mix64(base + 0ull), x, tgt, dgt);
        for (int att = 0; att < 900; ++att){
            AttLd nxt = att_issue(mix64(base + (uint64_t)(att + 1)), x, tgt, dgt);
            float gx = (cur.cc - cur.a) + 2.0f*(cur.e - cur.d) + (cur.h - cur.f);
            float gy = (cur.a + 2.0f*cur.b + cur.cc) - (cur.f + 2.0f*cur.g + cur.h);
            float e2 = gx*gx + gy*gy;
            bool pass = (cur.r == cur.rl) && (cur.c == cur.cl) && (e2 >= thr2) &&
                        (cur.dg > -0.001f && cur.dg < 80.0f) && (cur.tg != 80.0f);
            if (pass){
                sh = cur.rl; sw = cur.cl; gxs = gx; gys = gy; e2s = e2;
                break;
            }
            cur = nxt;
        }

        bool inb = false;
        float tA = 0.f, iA = 0.f;
        if (sh >= 0){
            float inv = rsqrtf(e2s);
            float cmul = gxs * inv;
            float rmul = gys * inv;
            if (!pdir) cmul = -cmul;

            // lane 'sub' owns dist[sub] (same split as the serial dist[4])
            uint64_t uu = mix64(base + 1000ull + (uint64_t)(sub >> 1));
            uint32_t half = (sub & 1) ? (uint32_t)(uu >> 32)
                                      : (uint32_t)(uu & 0xFFFFFFFFull);
            float dist = (float)(2u + half % 29u) * ((sub < 2) ? -1.0f : 1.0f);

            int cc2 = sw + (int)rintf(dist * cmul);
            int rr2 = sh + (int)rintf(dist * rmul);
            inb = (cc2 >= 0 && cc2 <= WW-1 && rr2 >= 0 && rr2 <= HH-1);
            int p = min(max(rr2, 0), HH-1)*WW + min(max(cc2, 0), WW-1);
            tA = tgt[p];
            iA = inp[p];
        }
        unsigned long long vb = __ballot((sh >= 0) && inb);
        bool valid = (sh >= 0) && (((vb >> grpb) & 0xFull) == 0xFull);

        float tB = __shfl_down(tA, 1);
        float iB = __shfl_down(iA, 1);

        if (valid && sub < 3){
            float ratio = (tA + 1e-6f) / (tB + 1e-6f);
            float adk = fabsf(tA - tB);
            mdiff = adk;
            bool eq = (ratio < 1.03f) && (ratio > 0.9708737864077669f);
            if (eq){
                float d = iA - iB;
                d2 = d*d; ad = adk;
            } else {
                float lab = (ratio >= 1.03f) ? 1.0f : -1.0f;
                un = log1pf(expf((iB - iA) * lab));
            }
        }
        if (valid && sub == 0) cntv = 3.0f;

        recs[(size_t)img * PAIRS * 4 + g] = make_float2(d2, ad);
    }

    // per-wave partials (plain stores)
    float m_ = mdiff, u_ = un, c_ = cntv;
    for (int off = 32; off; off >>= 1){
        m_ = fmaxf(m_, __shfl_down(m_, off));
        u_ += __shfl_down(u_, off);
        c_ += __shfl_down(c_, off);
    }
    if (lane == 0){
        int slot = jb*4 + (tid >> 6);
        ws[OFF_MD  + img * PSTRIDE + slot] = m_;
        ws[OFF_UN  + img * PSTRIDE + slot] = u_;
        ws[OFF_CNT + img * PSTRIDE + slot] = c_;
    }
}

// 4 blocks per image (XCD-pinned): redundant md reduce over 640 slots,
// quarter-scan of records + quarter of un/cnt slots, atomic accumulation into
// PADDED per-image slots; LAST block does the final cross-image reduce.
__global__ __launch_bounds__(256) void finish_kernel(
                               float* __restrict__ ws,
                               const float2* __restrict__ recs,
                               float* __restrict__ out){
    __shared__ float sred[4];
    __shared__ unsigned lastflag;
    int img = blockIdx.x & 7;                 // XCD-pinned (records L2-local)
    int q   = blockIdx.x >> 3;                // 0..3
    int tid = threadIdx.x;

    float mv = 0.0f;
    for (int s = tid; s < PSTRIDE; s += 256)
        mv = fmaxf(mv, ws[OFF_MD + img * PSTRIDE + s]);
    float md = block_reduce_max(mv, sred);
    float inv = 1.0f / (md + 1e-6f);

    float uv = 0.0f, cv = 0.0f;
    for (int s = q*QSLOT + tid; s < (q+1)*QSLOT; s += 256){
        uv += ws[OFF_UN  + img * PSTRIDE + s];
        cv += ws[OFF_CNT + img * PSTRIDE + s];
    }

    float eqs = 0.0f;
    const float2* sp = recs + (size_t)img * PAIRS * 4 + (size_t)q * QREC;
    for (int r = tid; r < QREC; r += 256){
        float2 s = sp[r];
        eqs += s.x * expf(-s.y * inv);
    }
    float loss = block_reduce_sum(eqs + uv, sred);
    float cnt  = block_reduce_sum(cv, sred);

    if (tid == 0){
        atomicAdd(&ws[OFF_RES + img*32 + 0], loss);
        atomicAdd(&ws[OFF_RES + img*32 + 1], cnt);
        __threadfence();                               // release
        unsigned old = atomicAdd((unsigned int*)&ws[OFF_CTR], 1u);
        lastflag = (old == (unsigned)(NIMG*FBLK - 1)) ? 1u : 0u;
    }
    __syncthreads();

    if (lastflag){
        __threadfence();                               // acquire
        float val = 0.0f, cv2 = 0.0f;
        if (tid < NIMG){
            float li = atomicAdd(&ws[OFF_RES + tid*32 + 0], 0.0f);
            float ci = atomicAdd(&ws[OFF_RES + tid*32 + 1], 0.0f);
            val = li / fmaxf(ci, 1.0f);
            cv2 = ci;
        }
        for (int off = 4; off; off >>= 1){
            val += __shfl_down(val, off);
            cv2 += __shfl_down(cv2, off);
        }
        if (tid == 0){
            out[0] = val / (float)NIMG;   // ALPHA = 1
            out[1] = cv2 / (float)NIMG;
        }
    }
}

extern "C" void kernel_launch(void* const* d_in, const int* in_sizes, int n_in,
                              void* d_out, int out_size, void* d_ws, size_t ws_size,
                              hipStream_t stream) {
    const float* inputs  = (const float*)d_in[0];
    const float* targets = (const float*)d_in[1];
    const float* images  = (const float*)d_in[2];
    const float* depth   = (const float*)d_in[3];
    float* out = (float*)d_out;

    float* ws    = (float*)d_ws;
    float2* recs = (float2*)((char*)d_ws + 131072);

    hipLaunchKernelGGL(edgemax_kernel, dim3(NSTRIPS/4 * NIMG), dim3(256), 0, stream,
                       images, ws);
    hipLaunchKernelGGL(sample_kernel, dim3(SBLK * NIMG), dim3(256), 0, stream,
                       inputs, targets, images, depth, ws, recs);
    hipLaunchKernelGGL(finish_kernel, dim3(NIMG * FBLK), dim3(256), 0, stream,
                       ws, recs, out);
}

// Round 15
// 36.700 us; speedup vs baseline: 1.3120x; 1.2543x over previous
//
#include <hip/hip_runtime.h>
#include <math.h>
#include <stdint.h>

#define NIMG 8
#define HH 1024
#define WW 1024
#define NPIX (HH*WW)
#define PAIRS 10000
#define STRIP 8
#define NSTRIPS 128          // strips per image (rows 1..1022, 8 rows each)
#define S1BLOCKS 40          // sample blocks per image
#define SEGCAP 30000         // worst-case eq segments per image (3*PAIRS)

// ws layout (floats). EVERY rendezvous word on its OWN 128B line, per-image
// lines at img*32 stride (one XCD touches each) — R11/R13 lesson. The finish
// data itself is ballot-COMPACTED eq segments (~1.2k/image, ~10 KB) written
// and read via memory-side atomics (atomicExch / atomicAdd(·,0)), so
// correctness does NOT depend on the blockIdx->XCD mapping heuristic.
// [OFF_EDGE .. +1024)   per-strip squared-sobel max (plain stores, k1;
//                       cross-kernel visibility via dispatch-boundary flush)
// [OFF_MDI  + img*32]   per-image maxdiff bits (uint atomicMax)
// [OFF_DONE + img*32]   per-image done counters (uint)
// [OFF_UN   + img*32]   per-image unequal-loss accum (float atomic)
// [OFF_CNT  + img*32]   per-image valid-count accum (float atomic)
// [OFF_SEGC + img*32]   per-image eq-segment counters (uint)
// [OFF_GL] [OFF_GC] [OFF_IMGD]  global accums, own lines
// byte 65536: segs ull[NIMG][SEGCAP] — packed {d2,ad} eq segments
#define OFF_EDGE 0
#define OFF_MDI  4096
#define OFF_DONE 4352
#define OFF_UN   4608
#define OFF_CNT  4864
#define OFF_SEGC 5120
#define OFF_GL   5376
#define OFF_GC   5408
#define OFF_IMGD 5440
#define ZERO_N   1376        // zero ws[4096 .. 5472)

__device__ __forceinline__ uint64_t mix64(uint64_t x){
    x += 0x9E3779B97F4A7C15ull;
    x = (x ^ (x >> 30)) * 0xBF58476D1CE4E5B9ull;
    x = (x ^ (x >> 27)) * 0x94D049BB133111EBull;
    return x ^ (x >> 31);
}

__device__ __forceinline__ float block_reduce_max(float v, float* sm){
    for (int off = 32; off; off >>= 1)
        v = fmaxf(v, __shfl_down(v, off));
    int wv = threadIdx.x >> 6, lane = threadIdx.x & 63;
    if (lane == 0) sm[wv] = v;
    __syncthreads();
    if (threadIdx.x == 0)
        sm[0] = fmaxf(fmaxf(sm[0], sm[1]), fmaxf(sm[2], sm[3]));
    __syncthreads();
    float r = sm[0];
    __syncthreads();
    return r;
}

__device__ __forceinline__ float block_reduce_sum(float v, float* sm){
    for (int off = 32; off; off >>= 1)
        v += __shfl_down(v, off);
    int wv = threadIdx.x >> 6, lane = threadIdx.x & 63;
    if (lane == 0) sm[wv] = v;
    __syncthreads();
    if (threadIdx.x == 0)
        sm[0] = sm[0] + sm[1] + sm[2] + sm[3];
    __syncthreads();
    float r = sm[0];
    __syncthreads();
    return r;
}

__device__ __forceinline__ void load16(const float* __restrict__ p, float* d){
    const float4* q = (const float4*)p;
    float4 v0 = q[0], v1 = q[1], v2 = q[2], v3 = q[3];
    d[0]=v0.x; d[1]=v0.y; d[2]=v0.z; d[3]=v0.w;
    d[4]=v1.x; d[5]=v1.y; d[6]=v1.z; d[7]=v1.w;
    d[8]=v2.x; d[9]=v2.y; d[10]=v2.z; d[11]=v2.w;
    d[12]=v3.x; d[13]=v3.y; d[14]=v3.z; d[15]=v3.w;
}

// One wave owns a 1024-wide row span (16 cols/lane), rolls 3 rows in registers,
// separable sobel, cross-lane neighbors via shuffles, max of SQUARED magnitude.
// Block 0 zeroes this launch's padded atomic slots (boundary-separated).
__global__ __launch_bounds__(256) void edgemax_kernel(const float* __restrict__ images,
                                                      float* __restrict__ ws){
    if (blockIdx.x == 0){
        for (int i = threadIdx.x; i < ZERO_N; i += 256)
            ws[OFF_MDI + i] = 0.0f;
    }

    int img  = blockIdx.x & 7;                          // XCD-pinned
    int xb   = blockIdx.x >> 3;                         // 0..31
    const float* x = images + (size_t)img * 3 * NPIX;   // channel 0
    int wv   = threadIdx.x >> 6;
    int lane = threadIdx.x & 63;
    int strip = xb * 4 + wv;                            // 0..127
    int r0 = 1 + strip * STRIP;
    int r1 = min(r0 + STRIP - 1, HH - 2);
    int c0 = lane * 16;

    float a[16], b[16], n[16];
    load16(x + (size_t)(r0-1)*WW + c0, a);
    load16(x + (size_t)r0*WW + c0, b);

    float m = 0.0f;
    for (int r = r0; r <= r1; ++r){
        load16(x + (size_t)(r+1)*WW + c0, n);
        float sx[16], dy[16];
        #pragma unroll
        for (int i = 0; i < 16; ++i){
            sx[i] = a[i] + 2.0f*b[i] + n[i];
            dy[i] = a[i] - n[i];
        }
        float sxl = __shfl_up(sx[15], 1);
        float sxr = __shfl_down(sx[0], 1);
        float dyl = __shfl_up(dy[15], 1);
        float dyr = __shfl_down(dy[0], 1);
        #pragma unroll
        for (int j = 0; j < 16; ++j){
            float sl = (j == 0)  ? sxl : sx[j-1];
            float sr = (j == 15) ? sxr : sx[j+1];
            float dl = (j == 0)  ? dyl : dy[j-1];
            float dr = (j == 15) ? dyr : dy[j+1];
            float gx = sr - sl;
            float gy = dl + 2.0f*dy[j] + dr;
            float e2 = gx*gx + gy*gy;
            int c = c0 + j;
            if (c >= 1 && c <= WW-2) m = fmaxf(m, e2);
        }
        #pragma unroll
        for (int i = 0; i < 16; ++i){ a[i] = b[i]; b[i] = n[i]; }
    }
    for (int off = 32; off; off >>= 1)
        m = fmaxf(m, __shfl_down(m, off));
    if (lane == 0)
        ws[OFF_EDGE + img * NSTRIPS + strip] = m;
}

// One rejection attempt's loaded state (loads issued eagerly, clamped).
struct AttLd {
    int r, c, rl, cl;
    float a, b, cc, d, e, f, g, h, dg, tg;
};

__device__ __forceinline__ AttLd att_issue(uint64_t u,
        const float* __restrict__ x, const float* __restrict__ tgt,
        const float* __restrict__ dgt){
    AttLd s;
    uint32_t pix = (uint32_t)(u >> 44);                // 20-bit uniform
    s.r  = (int)(pix >> 10);
    s.c  = (int)(pix & (WW - 1));
    s.rl = min(max(s.r, 1), HH-2);
    s.cl = min(max(s.c, 1), WW-2);
    const float* p0 = x + (size_t)(s.rl-1)*WW + s.cl;
    const float* p1 = x + (size_t)s.rl*WW + s.cl;
    const float* p2 = x + (size_t)(s.rl+1)*WW + s.cl;
    s.a = p0[-1]; s.b = p0[0]; s.cc = p0[1];
    s.d = p1[-1];               s.e = p1[1];
    s.f = p2[-1]; s.g = p2[0];  s.h = p2[1];
    s.dg = dgt[s.rl*WW + s.cl];
    s.tg = tgt[s.rl*WW + s.cl];
    return s;
}

// Sample (1 thread/pair, R12's pipelined serial rejection) + ballot-compacted
// eq segments (memory-side atomics); 40th-arriver block per image finishes
// from the ~10 KB compacted stream; 8th image finisher writes out.
__global__ __launch_bounds__(256) void sample_finish_kernel(
                               const float* __restrict__ inputs,
                               const float* __restrict__ targets,
                               const float* __restrict__ images,
                               const float* __restrict__ depth_gt,
                               float* __restrict__ ws,
                               unsigned long long* __restrict__ segs,
                               float* __restrict__ out){
    __shared__ float sred[4];
    __shared__ unsigned flag1;
    int img  = blockIdx.x & 7;                // XCD-pinned
    int jb   = blockIdx.x >> 3;               // 0..39
    int tid  = threadIdx.x;
    int lane = tid & 63;
    int j    = jb * 256 + tid;
    const float* x   = images   + (size_t)img * 3 * NPIX;
    const float* inp = inputs   + (size_t)img * NPIX;
    const float* tgt = targets  + (size_t)img * NPIX;
    const float* dgt = depth_gt + (size_t)img * NPIX;

    float ev = 0.0f;
    if (tid < NSTRIPS) ev = ws[OFF_EDGE + img * NSTRIPS + tid];
    float thr2 = 0.01f * block_reduce_max(ev, sred);

    float mdiff = 0.0f, un = 0.0f, cntv = 0.0f;
    float d2a[3] = {0.f,0.f,0.f}, ada[3] = {0.f,0.f,0.f};
    bool  eqf[3] = {false,false,false};

    if (j < PAIRS){
        uint64_t base = ((uint64_t)(img * PAIRS + j)) << 10;
        bool pdir = (mix64(((uint64_t)(NIMG * PAIRS + img)) << 10) & 1ull) != 0ull;

        int sh = -1, sw = -1;
        float gxs = 0.f, gys = 0.f, e2s = 1.f;

        AttLd cur = att_issue(mix64(base + 0ull), x, tgt, dgt);
        for (int att = 0; att < 900; ++att){
            AttLd nxt = att_issue(mix64(base + (uint64_t)(att + 1)), x, tgt, dgt);
            float gx = (cur.cc - cur.a) + 2.0f*(cur.e - cur.d) + (cur.h - cur.f);
            float gy = (cur.a + 2.0f*cur.b + cur.cc) - (cur.f + 2.0f*cur.g + cur.h);
            float e2 = gx*gx + gy*gy;
            bool pass = (cur.r == cur.rl) && (cur.c == cur.cl) && (e2 >= thr2) &&
                        (cur.dg > -0.001f && cur.dg < 80.0f) && (cur.tg != 80.0f);
            if (pass){
                sh = cur.rl; sw = cur.cl; gxs = gx; gys = gy; e2s = e2;
                break;
            }
            cur = nxt;
        }

        if (sh >= 0){
            float inv = rsqrtf(e2s);
            float cmul = gxs * inv;
            float rmul = gys * inv;
            if (!pdir) cmul = -cmul;

            uint64_t u0 = mix64(base + 1000ull);
            uint64_t u1 = mix64(base + 1001ull);
            float dist[4];
            dist[0] = -(float)(2u + (uint32_t)(u0 & 0xFFFFFFFFull) % 29u);
            dist[1] = -(float)(2u + (uint32_t)(u0 >> 32) % 29u);
            dist[2] =  (float)(2u + (uint32_t)(u1 & 0xFFFFFFFFull) % 29u);
            dist[3] =  (float)(2u + (uint32_t)(u1 >> 32) % 29u);

            int rowc[4], colc[4];
            bool valid = true;
            #pragma unroll
            for (int k = 0; k < 4; ++k){
                int cc2 = sw + (int)rintf(dist[k] * cmul);
                int rr2 = sh + (int)rintf(dist[k] * rmul);
                if (cc2 < 0 || cc2 > WW-1 || rr2 < 0 || rr2 > HH-1) valid = false;
                colc[k] = min(max(cc2, 0), WW-1);
                rowc[k] = min(max(rr2, 0), HH-1);
            }

            if (valid){
                float t4[4], i4[4];
                #pragma unroll
                for (int k = 0; k < 4; ++k){
                    int p = rowc[k]*WW + colc[k];
                    t4[k] = tgt[p];
                    i4[k] = inp[p];
                }
                #pragma unroll
                for (int k = 0; k < 3; ++k){
                    float tA = t4[k], tB = t4[k+1];
                    float ratio = (tA + 1e-6f) / (tB + 1e-6f);
                    float adk = fabsf(tA - tB);
                    mdiff = fmaxf(mdiff, adk);
                    bool eq = (ratio < 1.03f) && (ratio > 0.9708737864077669f);
                    if (eq){
                        float d = i4[k] - i4[k+1];
                        d2a[k] = d*d; ada[k] = adk; eqf[k] = true;
                    } else {
                        float lab = (ratio >= 1.03f) ? 1.0f : -1.0f;
                        un += log1pf(expf((i4[k+1] - i4[k]) * lab));
                    }
                }
                cntv = 3.0f;
            }
        }
    }

    // ---- ballot-compact eq segments (1 counter RMW/wave; data via
    //      memory-side atomicExch so visibility is XCD-independent) ----
    {
        unsigned long long m0 = __ballot(eqf[0]);
        unsigned long long m1 = __ballot(eqf[1]);
        unsigned long long m2 = __ballot(eqf[2]);
        int c0 = __popcll(m0), c1 = __popcll(m1), c2 = __popcll(m2);
        int wavetot = c0 + c1 + c2;
        unsigned basei = 0;
        if (lane == 0 && wavetot)
            basei = atomicAdd((unsigned int*)&ws[OFF_SEGC + img*32],
                              (unsigned)wavetot);
        basei = (unsigned)__shfl((int)basei, 0);
        unsigned long long below = (1ull << lane) - 1ull;
        unsigned long long* sp = segs + (size_t)img * SEGCAP;
        #pragma unroll
        for (int k = 0; k < 3; ++k){
            if (eqf[k]){
                unsigned off = basei
                    + (k > 0 ? (unsigned)c0 : 0u)
                    + (k > 1 ? (unsigned)c1 : 0u)
                    + (unsigned)__popcll(((k==0)?m0:(k==1)?m1:m2) & below);
                unsigned long long v = ((unsigned long long)__float_as_uint(ada[k]) << 32)
                                     | (unsigned long long)__float_as_uint(d2a[k]);
                atomicExch(&sp[off], v);
            }
        }
    }

    // ---- per-block accumulation into padded per-image atomic lines ----
    float mdb = block_reduce_max(mdiff, sred);  // barrier drains every wave's
    float unb = block_reduce_sum(un, sred);     // vmem (incl. seg exchanges)
    float cnb = block_reduce_sum(cntv, sred);
    if (tid == 0){
        if (mdb > 0.0f)
            atomicMax((unsigned int*)&ws[OFF_MDI + img*32], __float_as_uint(mdb));
        atomicAdd(&ws[OFF_UN  + img*32], unb);
        atomicAdd(&ws[OFF_CNT + img*32], cnb);
        asm volatile("s_waitcnt vmcnt(0)" ::: "memory");   // land before done++
        unsigned old = atomicAdd((unsigned int*)&ws[OFF_DONE + img*32], 1u);
        flag1 = (old == (unsigned)(S1BLOCKS - 1)) ? 1u : 0u;
    }
    __syncthreads();

    // ---- 40th arriver: finish this image from ~10 KB compacted segs ----
    if (flag1){
        float md = __uint_as_float(
            atomicAdd((unsigned int*)&ws[OFF_MDI + img*32], 0u));
        float inv = 1.0f / (md + 1e-6f);
        unsigned nseg = atomicAdd((unsigned int*)&ws[OFF_SEGC + img*32], 0u);
        unsigned long long* sp = segs + (size_t)img * SEGCAP;

        float eqs = 0.0f;
        for (unsigned r = tid; r < nseg; r += 256){
            unsigned long long v = atomicAdd(&sp[r], 0ull);   // coherent read
            float d2v = __uint_as_float((unsigned)(v & 0xFFFFFFFFull));
            float adv = __uint_as_float((unsigned)(v >> 32));
            eqs += d2v * expf(-adv * inv);
        }
        eqs = block_reduce_sum(eqs, sred);

        if (tid == 0){
            float unv = atomicAdd(&ws[OFF_UN  + img*32], 0.0f);
            float cnv = atomicAdd(&ws[OFF_CNT + img*32], 0.0f);
            float Li = (eqs + unv) / fmaxf(cnv, 1.0f);   // ALPHA = 1
            atomicAdd(&ws[OFF_GL], Li);
            atomicAdd(&ws[OFF_GC], cnv);
            asm volatile("s_waitcnt vmcnt(0)" ::: "memory");
            unsigned o2 = atomicAdd((unsigned int*)&ws[OFF_IMGD], 1u);
            if (o2 == (unsigned)(NIMG - 1)){
                float gl = atomicAdd(&ws[OFF_GL], 0.0f);
                float gc = atomicAdd(&ws[OFF_GC], 0.0f);
                out[0] = gl / (float)NIMG;
                out[1] = gc / (float)NIMG;
            }
        }
    }
}

extern "C" void kernel_launch(void* const* d_in, const int* in_sizes, int n_in,
                              void* d_out, int out_size, void* d_ws, size_t ws_size,
                              hipStream_t stream) {
    const float* inputs  = (const float*)d_in[0];
    const float* targets = (const float*)d_in[1];
    const float* images  = (const float*)d_in[2];
    const float* depth   = (const float*)d_in[3];
    float* out = (float*)d_out;

    float* ws = (float*)d_ws;
    unsigned long long* segs = (unsigned long long*)((char*)d_ws + 65536);

    hipLaunchKernelGGL(edgemax_kernel, dim3(NSTRIPS/4 * NIMG), dim3(256), 0, stream,
                       images, ws);
    hipLaunchKernelGGL(sample_finish_kernel, dim3(S1BLOCKS * NIMG), dim3(256), 0, stream,
                       inputs, targets, images, depth, ws, segs, out);
}